// Round 16
// baseline (33.728 us; speedup 1.0000x reference)
//
#include <hip/hip_runtime.h>
#include <hip/hip_bf16.h>

#define NB 4
#define NH 16
#define SEQ 2048
#define EMB 512
#define DH 32
#define CHUNKQ 64
#define WIN 256

typedef __attribute__((ext_vector_type(8))) short short8;
typedef __attribute__((ext_vector_type(4))) float f32x4;

// packed f32x2 -> bf16x2 (RNE); HW-validated rounds 3/6/8
__device__ __forceinline__ unsigned cvt_pk_bf16(float lo, float hi) {
    unsigned r;
    asm("v_cvt_pk_bf16_f32 %0, %1, %2" : "=v"(r) : "v"(lo), "v"(hi));
    return r;
}

// ============================================================================
// Split-K path: each (b,h,chunk) task -> 2 blocks, each owning half the key
// window (KT/2 in {32..160}, multiple of 32). No max-subtraction anywhere, so
// partial (O, sum_exp) combine by simple addition in a second kernel.
// Per-block LDS 27392B -> 5 blocks/CU (vs r8's 3): Ks[160][36] 11520 +
// Vt[32][168] 10752 + Pbuf 4x[16][20]u32 5120. Mechanics verbatim r8.
// Partials in d_ws: [4096][2112 f32] = 34.6MB (O[64][32] + srow[64]).
// ============================================================================

__global__ __launch_bounds__(256, 5)
void attn_split_kernel(const float* __restrict__ q, const float* __restrict__ k,
                       const float* __restrict__ v, float* __restrict__ part)
{
    constexpr int KSTR = 36;
    constexpr int VSTR = 168;
    constexpr int PSTR = 20;
    __shared__ __align__(16) ushort Ks[160 * KSTR];
    __shared__ __align__(16) ushort Vt[32 * VSTR];
    __shared__ __align__(16) unsigned Pbuf[4][16 * PSTR];

    // XCD swizzle (4096 = 8*512, bijective); adjacent bids = same task's splits
    const unsigned bid = (blockIdx.x & 7) * 512 + (blockIdx.x >> 3);
    const int s    = bid & 1;           // split id
    const int task = bid >> 1;          // 0..2047
    const int cid  = task & 31;
    const int h    = (task >> 5) & 15;
    const int b    = task >> 9;
    const int q0   = cid * CHUNKQ;
    const int hi   = q0 + CHUNKQ;
    const int kstart = (hi - 320 > 0) ? (hi - 320) : 0;
    const int KT   = hi - kstart;       // 64..320, multiple of 64
    const int half = KT >> 1;           // 32..160, multiple of 32
    const int ks0  = kstart + s * half; // this split's key range [ks0, ks0+half)

    const int tid = threadIdx.x;
    const int e4  = (tid & 7) * 4;
    const int r0  = tid >> 3;
    const int d2  = (tid & 15) * 2;
    const int kp  = tid >> 4;

    // staging loads (unconditional; max row = ks0+159 <= 2047, verified:
    // KT=320 -> ks0 <= 1888; KT<320 only for cid<4 -> ks0 <= 128)
    float4 fk[5];
    float2 va[5], vb[5];
    #pragma unroll
    for (int it = 0; it < 5; ++it) {
        const size_t kbase = (size_t)(b * SEQ + ks0 + r0 + it * 32) * EMB + h * DH + e4;
        fk[it] = *(const float4*)(k + kbase);
        const size_t vbase = (size_t)(b * SEQ + ks0 + 32 * it + 2 * kp) * EMB + h * DH + d2;
        va[it] = *(const float2*)(v + vbase);
        vb[it] = *(const float2*)(v + vbase + EMB);
    }

    const int w   = tid >> 6;
    const int l   = tid & 63;
    const int l16 = l & 15;
    const int kg  = l >> 4;
    const int k0  = kg * 8;

    const float* qrow = q + ((size_t)(b * SEQ + q0 + 16 * w + l16) * EMB + h * DH + k0);
    const float4 qa = *(const float4*)qrow;
    const float4 qc = *(const float4*)(qrow + 4);
    union { short8 s8; unsigned u[4]; } qb;
    qb.u[0] = cvt_pk_bf16(qa.x, qa.y);
    qb.u[1] = cvt_pk_bf16(qa.z, qa.w);
    qb.u[2] = cvt_pk_bf16(qc.x, qc.y);
    qb.u[3] = cvt_pk_bf16(qc.z, qc.w);

    #pragma unroll
    for (int it = 0; it < 5; ++it) {
        uint2 kw;
        kw.x = cvt_pk_bf16(fk[it].x, fk[it].y);
        kw.y = cvt_pk_bf16(fk[it].z, fk[it].w);
        *(uint2*)(Ks + (r0 + it * 32) * KSTR + e4) = kw;
        *(unsigned*)(Vt + (d2 + 0) * VSTR + 32 * it + 2 * kp) = cvt_pk_bf16(va[it].x, vb[it].x);
        *(unsigned*)(Vt + (d2 + 1) * VSTR + 32 * it + 2 * kp) = cvt_pk_bf16(va[it].y, vb[it].y);
    }
    __syncthreads();

    const float scale = 0.17677669529663687f;
    const int   iq    = q0 + 16 * w + l16;
    const int   lowk  = iq - (WIN - 1);
    unsigned* pw = &Pbuf[w][l16 * PSTR];

    const f32x4 zero = {0.f, 0.f, 0.f, 0.f};
    f32x4 o0 = zero, o1 = zero;
    float srow = 0.f;

    #pragma unroll
    for (int t = 0; t < 5; ++t) {
        if (t * 32 < half) {
            const short8 ka = *(const short8*)(Ks + (32 * t + l16) * KSTR + k0);
            const short8 kb = *(const short8*)(Ks + (32 * t + 16 + l16) * KSTR + k0);
            f32x4 s_lo = __builtin_amdgcn_mfma_f32_16x16x32_bf16(ka, qb.s8, zero, 0, 0, 0);
            f32x4 s_hi = __builtin_amdgcn_mfma_f32_16x16x32_bf16(kb, qb.s8, zero, 0, 0, 0);

            const int kk = ks0 + 32 * t + 4 * kg;
            float p[8];
            #pragma unroll
            for (int r = 0; r < 4; ++r) {
                p[r]     = (kk + r      >= lowk) ? __expf(s_lo[r] * scale) : 0.f;
                p[r + 4] = (kk + r + 16 >= lowk) ? __expf(s_hi[r] * scale) : 0.f;
            }
            srow += ((p[0] + p[1]) + (p[2] + p[3])) + ((p[4] + p[5]) + (p[6] + p[7]));

            uint2 wlo, whi;
            wlo.x = cvt_pk_bf16(p[0], p[1]);  wlo.y = cvt_pk_bf16(p[2], p[3]);
            whi.x = cvt_pk_bf16(p[4], p[5]);  whi.y = cvt_pk_bf16(p[6], p[7]);
            *(uint2*)(pw + 2 * kg)     = wlo;
            *(uint2*)(pw + 8 + 2 * kg) = whi;
            const short8 pa = *(const short8*)(pw + 4 * kg);

            const short8 bv0 = *(const short8*)(Vt + l16 * VSTR + 32 * t + k0);
            const short8 bv1 = *(const short8*)(Vt + (16 + l16) * VSTR + 32 * t + k0);
            o0 = __builtin_amdgcn_mfma_f32_16x16x32_bf16(pa, bv0, o0, 0, 0, 0);
            o1 = __builtin_amdgcn_mfma_f32_16x16x32_bf16(pa, bv1, o1, 0, 0, 0);
        }
    }

    // partial store: P = [O 64x32][srow 64] f32 (2112 floats per split-block)
    float* P = part + (size_t)bid * 2112;
    #pragma unroll
    for (int r = 0; r < 4; ++r) {
        const int row = 16 * w + 4 * kg + r;
        P[row * 32 + l16]      = o0[r];
        P[row * 32 + 16 + l16] = o1[r];
    }
    srow += __shfl_xor(srow, 16);
    srow += __shfl_xor(srow, 32);      // srow(q=l16) in all kg groups
    if (kg == 0) P[2048 + 16 * w + l16] = srow;
}

__global__ __launch_bounds__(256, 8)
void attn_combine_kernel(const float* __restrict__ part, float* __restrict__ out)
{
    const int task = blockIdx.x;       // 0..2047
    const int cid  = task & 31;
    const int h    = (task >> 5) & 15;
    const int b    = task >> 9;
    const int q0   = cid * CHUNKQ;

    const float* A = part + (size_t)(task * 2) * 2112;
    const float* B = A + 2112;

    const int t  = threadIdx.x;        // 256
    const int qr = t >> 2;             // query row 0..63
    const int d8 = (t & 3) * 8;        // dim base 0,8,16,24

    const float inv = 1.0f / (A[2048 + qr] + B[2048 + qr]);
    const float4 a0 = *(const float4*)(A + qr * 32 + d8);
    const float4 a1 = *(const float4*)(A + qr * 32 + d8 + 4);
    const float4 b0 = *(const float4*)(B + qr * 32 + d8);
    const float4 b1 = *(const float4*)(B + qr * 32 + d8 + 4);

    float4 r0, r1;
    r0.x = (a0.x + b0.x) * inv;  r0.y = (a0.y + b0.y) * inv;
    r0.z = (a0.z + b0.z) * inv;  r0.w = (a0.w + b0.w) * inv;
    r1.x = (a1.x + b1.x) * inv;  r1.y = (a1.y + b1.y) * inv;
    r1.z = (a1.z + b1.z) * inv;  r1.w = (a1.w + b1.w) * inv;

    float* dst = out + (size_t)(b * SEQ + q0 + qr) * EMB + h * DH + d8;
    *(float4*)dst       = r0;
    *(float4*)(dst + 4) = r1;
}

// ============================================================================
// Fallback: r8 kernel verbatim (green, 26.4us) -- used if ws_size is short.
// ============================================================================

__global__ __launch_bounds__(256, 3)
void attn_chunk_kernel(const float* __restrict__ q, const float* __restrict__ k,
                       const float* __restrict__ v, float* __restrict__ out)
{
    constexpr int KSTR = 40;
    constexpr int VSTR = 328;
    constexpr int PSTR = 20;
    __shared__ __align__(16) ushort Ks[320 * KSTR];
    __shared__ __align__(16) ushort Vt[32 * VSTR];
    __shared__ __align__(16) unsigned Pbuf[4][16 * PSTR];

    const unsigned bid = (blockIdx.x & 7) * 256 + (blockIdx.x >> 3);
    const int cid = bid & 31;
    const int h   = (bid >> 5) & 15;
    const int b   = bid >> 9;
    const int q0  = cid * CHUNKQ;
    const int hi  = q0 + CHUNKQ;
    const int kstart = (hi - 320 > 0) ? (hi - 320) : 0;
    const int KT  = hi - kstart;

    const int tid = threadIdx.x;
    const int e4  = (tid & 7) * 4;
    const int r0  = tid >> 3;
    const int d2  = (tid & 15) * 2;
    const int kp  = tid >> 4;

    float4 fk[10];
    float2 va[10], vb[10];
    #pragma unroll
    for (int it = 0; it < 10; ++it) {
        const size_t kbase = (size_t)(b * SEQ + kstart + r0 + it * 32) * EMB + h * DH + e4;
        fk[it] = *(const float4*)(k + kbase);
        const size_t vbase = (size_t)(b * SEQ + kstart + 32 * it + 2 * kp) * EMB + h * DH + d2;
        va[it] = *(const float2*)(v + vbase);
        vb[it] = *(const float2*)(v + vbase + EMB);
    }

    const int w   = tid >> 6;
    const int l   = tid & 63;
    const int l16 = l & 15;
    const int kg  = l >> 4;
    const int k0  = kg * 8;

    const float* qrow = q + ((size_t)(b * SEQ + q0 + 16 * w + l16) * EMB + h * DH + k0);
    const float4 qa = *(const float4*)qrow;
    const float4 qc = *(const float4*)(qrow + 4);
    union { short8 s; unsigned u[4]; } qb;
    qb.u[0] = cvt_pk_bf16(qa.x, qa.y);
    qb.u[1] = cvt_pk_bf16(qa.z, qa.w);
    qb.u[2] = cvt_pk_bf16(qc.x, qc.y);
    qb.u[3] = cvt_pk_bf16(qc.z, qc.w);

    #pragma unroll
    for (int it = 0; it < 10; ++it) {
        uint2 kw;
        kw.x = cvt_pk_bf16(fk[it].x, fk[it].y);
        kw.y = cvt_pk_bf16(fk[it].z, fk[it].w);
        *(uint2*)(Ks + (r0 + it * 32) * KSTR + e4) = kw;
        *(unsigned*)(Vt + (d2 + 0) * VSTR + 32 * it + 2 * kp) = cvt_pk_bf16(va[it].x, vb[it].x);
        *(unsigned*)(Vt + (d2 + 1) * VSTR + 32 * it + 2 * kp) = cvt_pk_bf16(va[it].y, vb[it].y);
    }
    __syncthreads();

    const float scale = 0.17677669529663687f;
    const int   iq    = q0 + 16 * w + l16;
    const int   lowk  = iq - (WIN - 1);
    unsigned* pw = &Pbuf[w][l16 * PSTR];

    const f32x4 zero = {0.f, 0.f, 0.f, 0.f};
    f32x4 o0 = zero, o1 = zero;
    float srow = 0.f;

    #pragma unroll
    for (int t = 0; t < 10; ++t) {
        if (t * 32 < KT) {
            const short8 ka = *(const short8*)(Ks + (32 * t + l16) * KSTR + k0);
            const short8 kb = *(const short8*)(Ks + (32 * t + 16 + l16) * KSTR + k0);
            f32x4 s_lo = __builtin_amdgcn_mfma_f32_16x16x32_bf16(ka, qb.s, zero, 0, 0, 0);
            f32x4 s_hi = __builtin_amdgcn_mfma_f32_16x16x32_bf16(kb, qb.s, zero, 0, 0, 0);

            const int kk = kstart + 32 * t + 4 * kg;
            float p[8];
            #pragma unroll
            for (int r = 0; r < 4; ++r) {
                p[r]     = (kk + r      >= lowk) ? __expf(s_lo[r] * scale) : 0.f;
                p[r + 4] = (kk + r + 16 >= lowk) ? __expf(s_hi[r] * scale) : 0.f;
            }
            srow += ((p[0] + p[1]) + (p[2] + p[3])) + ((p[4] + p[5]) + (p[6] + p[7]));

            uint2 wlo, whi;
            wlo.x = cvt_pk_bf16(p[0], p[1]);  wlo.y = cvt_pk_bf16(p[2], p[3]);
            whi.x = cvt_pk_bf16(p[4], p[5]);  whi.y = cvt_pk_bf16(p[6], p[7]);
            *(uint2*)(pw + 2 * kg)     = wlo;
            *(uint2*)(pw + 8 + 2 * kg) = whi;
            const short8 pa = *(const short8*)(pw + 4 * kg);

            const short8 bv0 = *(const short8*)(Vt + l16 * VSTR + 32 * t + k0);
            const short8 bv1 = *(const short8*)(Vt + (16 + l16) * VSTR + 32 * t + k0);
            o0 = __builtin_amdgcn_mfma_f32_16x16x32_bf16(pa, bv0, o0, 0, 0, 0);
            o1 = __builtin_amdgcn_mfma_f32_16x16x32_bf16(pa, bv1, o1, 0, 0, 0);
        }
    }

    srow += __shfl_xor(srow, 16);
    srow += __shfl_xor(srow, 32);
    #pragma unroll
    for (int r = 0; r < 4; ++r) {
        const float sq  = __shfl(srow, 4 * kg + r);
        const float inv = 1.0f / sq;
        float* dst = out + (size_t)(b * SEQ + q0 + 16 * w + 4 * kg + r) * EMB + h * DH;
        dst[l16]      = o0[r] * inv;
        dst[16 + l16] = o1[r] * inv;
    }
}

extern "C" void kernel_launch(void* const* d_in, const int* in_sizes, int n_in,
                              void* d_out, int out_size, void* d_ws, size_t ws_size,
                              hipStream_t stream) {
    const float* q = (const float*)d_in[0];
    const float* k = (const float*)d_in[1];
    const float* v = (const float*)d_in[2];
    float* out = (float*)d_out;

    const size_t ws_needed = (size_t)4096 * 2112 * sizeof(float);   // 34.6 MB
    if (ws_size >= ws_needed) {
        float* part = (float*)d_ws;
        attn_split_kernel<<<4096, 256, 0, stream>>>(q, k, v, part);
        attn_combine_kernel<<<2048, 256, 0, stream>>>(part, out);
    } else {
        attn_chunk_kernel<<<NB * NH * (SEQ / CHUNKQ), 256, 0, stream>>>(q, k, v, out);
    }
}